// Round 2
// baseline (41.106 us; speedup 1.0000x reference)
//
#include <hip/hip_runtime.h>
#include <hip/hip_bf16.h>

// BoundaryLoss: out = mean_{n, c in 1..3} sum_{h,w} softmax[n,c,h,w]*dist[n,c,h,w]
// N=16, C=4, H=W=512.  PLANE4 = 512*512/4 = 65536 float4 per class plane.
// Block-contiguous mapping: 2048 blocks x 1536 float4 each; 128 blocks per n
// (PERN4 = 3*PLANE4 = 196608 = 128*1536), so each block is inside one n and
// all addressing except threadIdx.x is scalar (SGPR).

#define PLANE4 65536
#define PERN4 (3 * PLANE4)      // classes 1..3 per n
#define STRIDEN4 (4 * PLANE4)   // full per-n stride (C=4)
#define BLOCKS 2048
#define THREADS 256
#define ITERS 6                 // 1536 float4 per block / 256 threads

__global__ __launch_bounds__(THREADS) void bl_fused(const float4* __restrict__ sm,
                                                    const float4* __restrict__ dm,
                                                    float* __restrict__ out) {
    const int bid = blockIdx.x;
    const int n = bid >> 7;            // 128 blocks per n
    const int rb = (bid & 127) * (THREADS * ITERS);
    const int base = n * STRIDEN4 + PLANE4 + rb + threadIdx.x;  // skip class 0

    float4 a[ITERS], b[ITERS];
    #pragma unroll
    for (int k = 0; k < ITERS; ++k) a[k] = sm[base + k * THREADS];
    #pragma unroll
    for (int k = 0; k < ITERS; ++k) b[k] = dm[base + k * THREADS];

    float acc = 0.0f;
    #pragma unroll
    for (int k = 0; k < ITERS; ++k)
        acc += a[k].x * b[k].x + a[k].y * b[k].y + a[k].z * b[k].z + a[k].w * b[k].w;

    // wave64 reduce
    #pragma unroll
    for (int o = 32; o >= 1; o >>= 1) acc += __shfl_down(acc, o, 64);
    __shared__ float s[THREADS / 64];
    const int lane = threadIdx.x & 63;
    const int wid = threadIdx.x >> 6;
    if (lane == 0) s[wid] = acc;
    __syncthreads();
    if (threadIdx.x == 0) {
        float t = 0.0f;
        #pragma unroll
        for (int i = 0; i < THREADS / 64; ++i) t += s[i];
        atomicAdd(out, t * (1.0f / 48.0f));  // mean over N*(C-1) = 48
    }
}

extern "C" void kernel_launch(void* const* d_in, const int* in_sizes, int n_in,
                              void* d_out, int out_size, void* d_ws, size_t ws_size,
                              hipStream_t stream) {
    const float4* sm = (const float4*)d_in[0];  // softmax_output, fp32 NCHW
    // d_in[1] = target (int32) -- unused on the precomputed-distance-map path
    const float4* dm = (const float4*)d_in[2];  // distance_maps, fp32 NCHW
    float* out = (float*)d_out;

    hipMemsetAsync(out, 0, sizeof(float), stream);  // graph-capture legal
    bl_fused<<<BLOCKS, THREADS, 0, stream>>>(sm, dm, out);
}

// Round 3
// 22.086 us; speedup vs baseline: 1.8611x; 1.8611x over previous
//
#include <hip/hip_runtime.h>
#include <hip/hip_bf16.h>

// BoundaryLoss: out = mean_{n, c in 1..3} sum_{h,w} softmax[n,c,h,w]*dist[n,c,h,w]
// N=16, C=4, H=W=512.  PLANE4 = 512*512/4 = 65536 float4 per class plane.
//
// Two-kernel deterministic reduction (no atomics, no memset in the graph —
// round-2 showed a graph-captured 4B hipMemsetAsync fill node costing ~40us).
// Pass 1: 2048 blocks x 256 threads, block-contiguous: 128 blocks per n,
// 1536 float4 per block (6 per thread), all addressing scalar except tid.
// Pass 2: one block reduces the 2048 partials.

#define PLANE4 65536
#define PERN4 (3 * PLANE4)      // classes 1..3 per n
#define STRIDEN4 (4 * PLANE4)   // full per-n stride (C=4)
#define BLOCKS 2048
#define THREADS 256
#define ITERS 6                 // 1536 float4 per block / 256 threads

__global__ __launch_bounds__(THREADS) void bl_pass1(const float4* __restrict__ sm,
                                                    const float4* __restrict__ dm,
                                                    float* __restrict__ partial) {
    const int bid = blockIdx.x;
    const int n = bid >> 7;                       // 128 blocks per n
    const int rb = (bid & 127) * (THREADS * ITERS);
    const int base = n * STRIDEN4 + PLANE4 + rb + threadIdx.x;  // skip class 0

    float4 a[ITERS], b[ITERS];
    #pragma unroll
    for (int k = 0; k < ITERS; ++k) a[k] = sm[base + k * THREADS];
    #pragma unroll
    for (int k = 0; k < ITERS; ++k) b[k] = dm[base + k * THREADS];

    float acc = 0.0f;
    #pragma unroll
    for (int k = 0; k < ITERS; ++k)
        acc += a[k].x * b[k].x + a[k].y * b[k].y + a[k].z * b[k].z + a[k].w * b[k].w;

    // wave64 reduce
    #pragma unroll
    for (int o = 32; o >= 1; o >>= 1) acc += __shfl_down(acc, o, 64);
    __shared__ float s[THREADS / 64];
    const int lane = threadIdx.x & 63;
    const int wid = threadIdx.x >> 6;
    if (lane == 0) s[wid] = acc;
    __syncthreads();
    if (threadIdx.x == 0) {
        float t = 0.0f;
        #pragma unroll
        for (int i = 0; i < THREADS / 64; ++i) t += s[i];
        partial[bid] = t;
    }
}

__global__ __launch_bounds__(THREADS) void bl_pass2(const float4* __restrict__ partial4,
                                                    float* __restrict__ out) {
    // 2048 partials = 512 float4; 256 threads read 2 each.
    float4 p0 = partial4[threadIdx.x];
    float4 p1 = partial4[threadIdx.x + THREADS];
    float acc = p0.x + p0.y + p0.z + p0.w + p1.x + p1.y + p1.z + p1.w;
    #pragma unroll
    for (int o = 32; o >= 1; o >>= 1) acc += __shfl_down(acc, o, 64);
    __shared__ float s[THREADS / 64];
    const int lane = threadIdx.x & 63;
    const int wid = threadIdx.x >> 6;
    if (lane == 0) s[wid] = acc;
    __syncthreads();
    if (threadIdx.x == 0) {
        float t = 0.0f;
        #pragma unroll
        for (int i = 0; i < THREADS / 64; ++i) t += s[i];
        out[0] = t * (1.0f / 48.0f);  // mean over N*(C-1) = 48
    }
}

extern "C" void kernel_launch(void* const* d_in, const int* in_sizes, int n_in,
                              void* d_out, int out_size, void* d_ws, size_t ws_size,
                              hipStream_t stream) {
    const float4* sm = (const float4*)d_in[0];  // softmax_output, fp32 NCHW
    // d_in[1] = target (int32) -- unused on the precomputed-distance-map path
    const float4* dm = (const float4*)d_in[2];  // distance_maps, fp32 NCHW
    float* out = (float*)d_out;
    float* partial = (float*)d_ws;              // 2048 floats, << ws_size

    bl_pass1<<<BLOCKS, THREADS, 0, stream>>>(sm, dm, partial);
    bl_pass2<<<1, THREADS, 0, stream>>>((const float4*)partial, out);
}

// Round 5
// 19.240 us; speedup vs baseline: 2.1365x; 1.1480x over previous
//
#include <hip/hip_runtime.h>
#include <hip/hip_bf16.h>

// BoundaryLoss: out = mean_{n, c in 1..3} sum_{h,w} softmax[n,c,h,w]*dist[n,c,h,w]
// N=16, C=4, H=W=512.  PLANE4 = 512*512/4 = 65536 float4 per class plane.
//
// Two-kernel deterministic reduction (no atomics; no memset in graph — a
// graph-captured 4B fill node cost ~40us in round 2).
// Pass 1: 2048 blocks x 256 threads, block-contiguous: 128 blocks per n,
// 1536 float4 per block (6 per thread), scalar addressing, non-temporal
// streaming loads (zero reuse; per-replay poison fills evict L3 anyway).
// NOTE: __builtin_nontemporal_load needs a NATIVE vector type, not HIP's
// HIP_vector_type wrapper — use ext_vector_type(4) float.
// Pass 2: ONE WAVE (64 threads) reduces 2048 partials, shuffle-only.

typedef float vfloat4 __attribute__((ext_vector_type(4)));

#define PLANE4 65536
#define STRIDEN4 (4 * PLANE4)   // full per-n stride (C=4)
#define BLOCKS 2048
#define THREADS 256
#define ITERS 6                 // 1536 float4 per block / 256 threads

__global__ __launch_bounds__(THREADS) void bl_pass1(const vfloat4* __restrict__ sm,
                                                    const vfloat4* __restrict__ dm,
                                                    float* __restrict__ partial) {
    const int bid = blockIdx.x;
    const int n = bid >> 7;                       // 128 blocks per n
    const int rb = (bid & 127) * (THREADS * ITERS);
    const int base = n * STRIDEN4 + PLANE4 + rb + threadIdx.x;  // skip class 0

    vfloat4 a[ITERS], b[ITERS];
    #pragma unroll
    for (int k = 0; k < ITERS; ++k) {
        a[k] = __builtin_nontemporal_load(&sm[base + k * THREADS]);
        b[k] = __builtin_nontemporal_load(&dm[base + k * THREADS]);
    }

    float acc = 0.0f;
    #pragma unroll
    for (int k = 0; k < ITERS; ++k)
        acc += a[k].x * b[k].x + a[k].y * b[k].y + a[k].z * b[k].z + a[k].w * b[k].w;

    // wave64 reduce
    #pragma unroll
    for (int o = 32; o >= 1; o >>= 1) acc += __shfl_down(acc, o, 64);
    __shared__ float s[THREADS / 64];
    const int lane = threadIdx.x & 63;
    const int wid = threadIdx.x >> 6;
    if (lane == 0) s[wid] = acc;
    __syncthreads();
    if (threadIdx.x == 0) {
        float t = 0.0f;
        #pragma unroll
        for (int i = 0; i < THREADS / 64; ++i) t += s[i];
        partial[bid] = t;
    }
}

__global__ __launch_bounds__(64) void bl_pass2(const vfloat4* __restrict__ partial4,
                                               float* __restrict__ out) {
    // 2048 partials = 512 float4; one wave, 8 float4 per lane.
    float acc = 0.0f;
    #pragma unroll
    for (int k = 0; k < 8; ++k) {
        vfloat4 p = partial4[threadIdx.x + k * 64];
        acc += p.x + p.y + p.z + p.w;
    }
    #pragma unroll
    for (int o = 32; o >= 1; o >>= 1) acc += __shfl_down(acc, o, 64);
    if (threadIdx.x == 0) out[0] = acc * (1.0f / 48.0f);  // mean over N*(C-1)=48
}

extern "C" void kernel_launch(void* const* d_in, const int* in_sizes, int n_in,
                              void* d_out, int out_size, void* d_ws, size_t ws_size,
                              hipStream_t stream) {
    const vfloat4* sm = (const vfloat4*)d_in[0];  // softmax_output, fp32 NCHW
    // d_in[1] = target (int32) -- unused on the precomputed-distance-map path
    const vfloat4* dm = (const vfloat4*)d_in[2];  // distance_maps, fp32 NCHW
    float* out = (float*)d_out;
    float* partial = (float*)d_ws;                // 2048 floats, << ws_size

    bl_pass1<<<BLOCKS, THREADS, 0, stream>>>(sm, dm, partial);
    bl_pass2<<<1, 64, 0, stream>>>((const vfloat4*)partial, out);
}